// Round 10
// baseline (252.922 us; speedup 1.0000x reference)
//
#include <hip/hip_runtime.h>

// ---------------------------------------------------------------------------
// SAM vision attention (B=1, H=W=64, C=768, 12 heads x hd=64). fp32 I/O.
// cvt -> QKV proj (128-tile) -> rel_h/rel_w -> flash attn (split-K, dbuf)
//   -> combine -> out proj
// MFMA v_mfma_f32_16x16x32_bf16 layouts (guide-verified m89/m91):
//   A/B frag: [m|n = lane&15][k = (lane>>4)*8 + j]   (8 bf16 / lane, b128)
//   C/D     : col = lane&15, row = (lane>>4)*4 + reg (4 f32 / lane)
// R10: attn2 K/V double-buffered with raw s_barrier + s_waitcnt vmcnt(4)
// (compiler __syncthreads emits vmcnt(0) and would drain the prefetch).
// rel_h moved from LDS (16 KB) to registers + __shfl broadcast so dbuf fits
// at 3 blocks/CU (50 KB): per block only ki = sp*32..sp*32+31 are needed.
// ---------------------------------------------------------------------------

typedef __attribute__((ext_vector_type(8))) short bf16x8;
typedef __attribute__((ext_vector_type(4))) float f32x4;
typedef __attribute__((ext_vector_type(4))) short s16x4;
typedef __attribute__((ext_vector_type(2))) unsigned int u32x2;

__device__ __forceinline__ float b2f(unsigned short h) {
    union { unsigned int u; float f; } v; v.u = ((unsigned int)h) << 16; return v.f;
}
__device__ __forceinline__ float lo16f(unsigned int u) {
    union { unsigned int u; float f; } v; v.u = u << 16; return v.f;
}
__device__ __forceinline__ float hi16f(unsigned int u) {
    union { unsigned int u; float f; } v; v.u = u & 0xffff0000u; return v.f;
}
__device__ __forceinline__ unsigned short f2b(float f) {
    union { float f; unsigned int u; } v; v.f = f;
    unsigned int r = v.u + 0x7FFFu + ((v.u >> 16) & 1u);  // RNE
    return (unsigned short)(r >> 16);
}
__device__ __forceinline__ void gl_lds16(const void* g, void* l) {
    __builtin_amdgcn_global_load_lds(
        (const __attribute__((address_space(1))) void*)g,
        (__attribute__((address_space(3))) void*)l, 16, 0, 0);
}

// ---------------------------------------------------------------------------
// fp32 -> bf16 bulk convert into one contiguous region (quad-indexed).
// ---------------------------------------------------------------------------
__global__ __launch_bounds__(256) void cvt_bf16(
        const float* __restrict__ hs, const float* __restrict__ wq,
        const float* __restrict__ wk, const float* __restrict__ wv,
        const float* __restrict__ wo, const float* __restrict__ rph,
        const float* __restrict__ rpw, unsigned short* __restrict__ dst) {
    const int idx = blockIdx.x * 256 + threadIdx.x;
    if (idx >= 1380320) return;
    const float* src;
    int off;
    if      (idx < 786432)  { src = hs;  off = idx; }
    else if (idx < 933888)  { src = wq;  off = idx - 786432; }
    else if (idx < 1081344) { src = wk;  off = idx - 933888; }
    else if (idx < 1228800) { src = wv;  off = idx - 1081344; }
    else if (idx < 1376256) { src = wo;  off = idx - 1228800; }
    else if (idx < 1378288) { src = rph; off = idx - 1376256; }
    else                    { src = rpw; off = idx - 1378288; }
    const float4 v = ((const float4*)src)[off];
    s16x4 o;
    o[0] = (short)f2b(v.x); o[1] = (short)f2b(v.y);
    o[2] = (short)f2b(v.z); o[3] = (short)f2b(v.w);
    *(s16x4*)(dst + (size_t)idx * 4) = o;
}

// ---------------------------------------------------------------------------
// Fused QKV projection, 128x128 tile. z: 0->q, 1->k [n>>6][m][n&63];
// 2->v^T token-PERMUTED (token kk=i*16+quad*4+reg at slot (quad*4+reg)*4+i),
// stored via LDS transpose with coalesced b128 writes.
// ---------------------------------------------------------------------------
__launch_bounds__(256, 3)
__global__ void qkv128(const unsigned short* __restrict__ X,
                       const unsigned short* __restrict__ Wq,
                       const unsigned short* __restrict__ Wk,
                       const unsigned short* __restrict__ Wv,
                       const float* __restrict__ bq,
                       const float* __restrict__ bk,
                       const float* __restrict__ bv,
                       unsigned short* __restrict__ qb,
                       unsigned short* __restrict__ kb,
                       unsigned short* __restrict__ vtb) {
    __shared__ __align__(16) unsigned short sarena[8192];
    unsigned short* abuf = sarena;
    unsigned short* bbuf = sarena + 4096;
    const int tid = threadIdx.x, lane = tid & 63, w = tid >> 6;
    const int r = lane & 15, quad = lane >> 4;
    const int nt = blockIdx.x, mt = blockIdx.y, z = blockIdx.z;
    const unsigned short* W  = (z == 0) ? Wq : (z == 1) ? Wk : Wv;
    const float*          Bv = (z == 0) ? bq : (z == 1) ? bk : bv;
    unsigned short*     outp = (z == 0) ? qb : (z == 1) ? kb : vtb;

    const int c0 = w * 64 + lane, c1 = c0 + 256;
    const unsigned short* xs0 = X + (mt * 128 + (c0 & 127)) * 768 + (c0 >> 7) * 8;
    const unsigned short* xs1 = X + (mt * 128 + (c1 & 127)) * 768 + (c1 >> 7) * 8;
    const unsigned short* ws0 = W + (nt * 128 + (c0 & 127)) * 768 + (c0 >> 7) * 8;
    const unsigned short* ws1 = W + (nt * 128 + (c1 & 127)) * 768 + (c1 >> 7) * 8;

    const int wr = (w & 1) * 64, wc = (w >> 1) * 64;
    f32x4 acc[4][4] = {};
    for (int kt = 0; kt < 24; ++kt) {
        gl_lds16(xs0 + kt * 32, &abuf[w * 512]);
        gl_lds16(xs1 + kt * 32, &abuf[2048 + w * 512]);
        gl_lds16(ws0 + kt * 32, &bbuf[w * 512]);
        gl_lds16(ws1 + kt * 32, &bbuf[2048 + w * 512]);
        __syncthreads();
        bf16x8 af[4], bfr[4];
#pragma unroll
        for (int i = 0; i < 4; ++i)
            af[i] = *(const bf16x8*)&abuf[(quad * 128 + wr + i * 16 + r) * 8];
#pragma unroll
        for (int j = 0; j < 4; ++j)
            bfr[j] = *(const bf16x8*)&bbuf[(quad * 128 + wc + j * 16 + r) * 8];
#pragma unroll
        for (int i = 0; i < 4; ++i)
#pragma unroll
            for (int j = 0; j < 4; ++j)
                acc[i][j] = __builtin_amdgcn_mfma_f32_16x16x32_bf16(af[i], bfr[j], acc[i][j], 0, 0, 0);
        __syncthreads();
    }
    if (z < 2) {
#pragma unroll
        for (int j = 0; j < 4; ++j) {
            const int n = nt * 128 + wc + j * 16 + r;
            const float bias = Bv[n];
            const int nhi = n >> 6, nlo = n & 63;
#pragma unroll
            for (int i = 0; i < 4; ++i) {
#pragma unroll
                for (int reg = 0; reg < 4; ++reg) {
                    const int m = mt * 128 + wr + i * 16 + quad * 4 + reg;
                    outp[(nhi * 4096 + m) * 64 + nlo] = f2b(acc[i][j][reg] + bias);
                }
            }
        }
    } else {
#pragma unroll
        for (int pass = 0; pass < 2; ++pass) {
            if ((w >> 1) == pass) {
#pragma unroll
                for (int j = 0; j < 4; ++j) {
                    const int n_l = j * 16 + r;
                    const float bias = Bv[nt * 128 + pass * 64 + n_l];
                    const int sw = (n_l & 7) << 4;
#pragma unroll
                    for (int reg = 0; reg < 4; ++reg) {
                        const int tokb = (wr + (quad * 4 + reg) * 4) ^ sw;
                        u32x2 d2;
                        d2.x = (unsigned int)f2b(acc[0][j][reg] + bias)
                             | ((unsigned int)f2b(acc[1][j][reg] + bias) << 16);
                        d2.y = (unsigned int)f2b(acc[2][j][reg] + bias)
                             | ((unsigned int)f2b(acc[3][j][reg] + bias) << 16);
                        *(u32x2*)&sarena[n_l * 128 + tokb] = d2;
                    }
                }
            }
            __syncthreads();
#pragma unroll
            for (int c = 0; c < 4; ++c) {
                const int u = c * 256 + tid;
                const int n_l = u >> 4, g = u & 15;
                const int phys = n_l * 128 + ((g * 8) ^ ((n_l & 7) << 4));
                bf16x8 val = *(const bf16x8*)&sarena[phys];
                *(bf16x8*)&outp[(size_t)(nt * 128 + pass * 64 + n_l) * 4096
                                + mt * 128 + g * 8] = val;
            }
            __syncthreads();
        }
    }
}

// ---------------------------------------------------------------------------
// Output projection, 128x128 tile, fp32 row-major out.
// ---------------------------------------------------------------------------
__launch_bounds__(256, 3)
__global__ void out128(const unsigned short* __restrict__ X,
                       const unsigned short* __restrict__ W,
                       const float* __restrict__ Bv,
                       float* __restrict__ out) {
    __shared__ __align__(16) unsigned short abuf[4 * 128 * 8];
    __shared__ __align__(16) unsigned short bbuf[4 * 128 * 8];
    const int tid = threadIdx.x, lane = tid & 63, w = tid >> 6;
    const int r = lane & 15, quad = lane >> 4;
    const int nt = blockIdx.x, mt = blockIdx.y;

    const int c0 = w * 64 + lane, c1 = c0 + 256;
    const unsigned short* xs0 = X + (mt * 128 + (c0 & 127)) * 768 + (c0 >> 7) * 8;
    const unsigned short* xs1 = X + (mt * 128 + (c1 & 127)) * 768 + (c1 >> 7) * 8;
    const unsigned short* ws0 = W + (nt * 128 + (c0 & 127)) * 768 + (c0 >> 7) * 8;
    const unsigned short* ws1 = W + (nt * 128 + (c1 & 127)) * 768 + (c1 >> 7) * 8;

    const int wr = (w & 1) * 64, wc = (w >> 1) * 64;
    f32x4 acc[4][4] = {};
    for (int kt = 0; kt < 24; ++kt) {
        gl_lds16(xs0 + kt * 32, &abuf[w * 512]);
        gl_lds16(xs1 + kt * 32, &abuf[2048 + w * 512]);
        gl_lds16(ws0 + kt * 32, &bbuf[w * 512]);
        gl_lds16(ws1 + kt * 32, &bbuf[2048 + w * 512]);
        __syncthreads();
        bf16x8 af[4], bfr[4];
#pragma unroll
        for (int i = 0; i < 4; ++i)
            af[i] = *(const bf16x8*)&abuf[(quad * 128 + wr + i * 16 + r) * 8];
#pragma unroll
        for (int j = 0; j < 4; ++j)
            bfr[j] = *(const bf16x8*)&bbuf[(quad * 128 + wc + j * 16 + r) * 8];
#pragma unroll
        for (int i = 0; i < 4; ++i)
#pragma unroll
            for (int j = 0; j < 4; ++j)
                acc[i][j] = __builtin_amdgcn_mfma_f32_16x16x32_bf16(af[i], bfr[j], acc[i][j], 0, 0, 0);
        __syncthreads();
    }
#pragma unroll
    for (int j = 0; j < 4; ++j) {
        const int n = nt * 128 + wc + j * 16 + r;
        const float bias = Bv[n];
#pragma unroll
        for (int i = 0; i < 4; ++i) {
#pragma unroll
            for (int reg = 0; reg < 4; ++reg) {
                const int m = mt * 128 + wr + i * 16 + quad * 4 + reg;
                out[m * 768 + n] = acc[i][j][reg] + bias;
            }
        }
    }
}

// ---------------------------------------------------------------------------
// rel_h / rel_w: per (head, a) 64x64x64 GEMM against gathered rel_pos rows.
// mode 0 (rel_h) output is PRE-SCALED by log2(e) (consumed only inside exp2).
// ---------------------------------------------------------------------------
__launch_bounds__(256, 4)
__global__ void relk(const unsigned short* __restrict__ qbuf,
                     const unsigned short* __restrict__ rph,
                     const unsigned short* __restrict__ rpw,
                     unsigned short* __restrict__ rh,
                     unsigned short* __restrict__ rw) {
    __shared__ __align__(16) unsigned short abuf[8 * 64 * 8];
    __shared__ __align__(16) unsigned short bbuf[8 * 64 * 8];
    const int tid = threadIdx.x;
    const int lane = tid & 63, w = tid >> 6;
    const int r = lane & 15, quad = lane >> 4;
    const int a = blockIdx.x, h = blockIdx.y, mode = blockIdx.z;
    const unsigned short* rp = mode ? rpw : rph;
    const float osc = mode ? 1.0f : 1.44269504f;

#pragma unroll
    for (int gg = 0; gg < 2; ++gg) {
        const int g = w * 2 + gg;
        const int arow = mode ? (h * 4096 + lane * 64 + a) : (h * 4096 + a * 64 + lane);
        gl_lds16(qbuf + arow * 64 + g * 8, &abuf[g * 512]);
        const int bidx = a - lane + 63;
        gl_lds16(rp + bidx * 64 + g * 8, &bbuf[g * 512]);
    }
    __syncthreads();

    f32x4 acc[4] = {};
#pragma unroll
    for (int s = 0; s < 2; ++s) {
        bf16x8 af = *(const bf16x8*)&abuf[((s * 4 + quad) * 64 + w * 16 + r) * 8];
#pragma unroll
        for (int j = 0; j < 4; ++j) {
            bf16x8 bfr = *(const bf16x8*)&bbuf[((s * 4 + quad) * 64 + j * 16 + r) * 8];
            acc[j] = __builtin_amdgcn_mfma_f32_16x16x32_bf16(af, bfr, acc[j], 0, 0, 0);
        }
    }
    unsigned short* out = mode ? rw : rh;
#pragma unroll
    for (int j = 0; j < 4; ++j) {
#pragma unroll
        for (int reg = 0; reg < 4; ++reg) {
            const int m = w * 16 + quad * 4 + reg, n = j * 16 + r;
            const int t = mode ? (h * 4096 + m * 64 + a) : (h * 4096 + a * 64 + m);
            out[t * 64 + n] = f2b(acc[j][reg] * osc);
        }
    }
}

// ---------------------------------------------------------------------------
// Flash attention, split-K + double-buffered K/V. Block = 128-query tile
// (2 qgroups of 16 per wave); split sp covers key tiles sp*32..sp*32+31.
// Raw s_barrier + s_waitcnt vmcnt(4) keeps the next tile's 4 staging loads
// in flight across the barrier. rel_h held in registers (one bf16-pair per
// (g,reg) per lane covers ki = sp*32 + r*2 + {0,1}); broadcast per tile-pair
// via one __shfl. Fixed softmax ref (m=0); l via ones-MFMA row-sum.
// LDS: 16 (K dbuf) + 16 (V dbuf) + 18 (P) = 50 KB -> 3 blocks/CU.
// ---------------------------------------------------------------------------
__launch_bounds__(256, 3)
__global__ void attn2(const unsigned short* __restrict__ qbuf,
                      const unsigned short* __restrict__ kbuf,
                      const unsigned short* __restrict__ vtbuf,
                      const unsigned short* __restrict__ rhb,
                      const unsigned short* __restrict__ rwb,
                      float* __restrict__ po, float* __restrict__ lp) {
    __shared__ __align__(16) unsigned short skb[2][4096];  // K [d_oct][key][8]
    __shared__ __align__(16) unsigned short svb[2][4096];  // V^T [scol_oct][d][8]
    __shared__ __align__(16) unsigned short spb[9216];     // P x2 groups, stride 72
    const int tid = threadIdx.x;
    const int lane = tid & 63, w = tid >> 6;
    const int r = lane & 15, quad = lane >> 4;
    const int qt = blockIdx.x, h = blockIdx.y, sp = blockIdx.z;
    const float L2E = 1.44269504f;
    const float SC = 0.125f * L2E;

    // Q frags for both qgroups
    bf16x8 qf[2][2];
#pragma unroll
    for (int g = 0; g < 2; ++g) {
        const unsigned short* qrow =
            qbuf + (h * 4096 + qt * 128 + g * 64 + w * 16 + r) * 64;
        qf[g][0] = *(const bf16x8*)(qrow + quad * 8);
        qf[g][1] = *(const bf16x8*)(qrow + 32 + quad * 8);
    }
    // rel_w * log2e, tile-invariant
    float rwL[2][4][4];
#pragma unroll
    for (int g = 0; g < 2; ++g) {
        const unsigned short* rwrow = rwb + (h * 4096 + qt * 128 + g * 64) * 64;
#pragma unroll
        for (int reg = 0; reg < 4; ++reg) {
            const int ql = w * 16 + quad * 4 + reg;
#pragma unroll
            for (int j = 0; j < 4; ++j)
                rwL[g][j][reg] = b2f(rwrow[ql * 64 + j * 16 + r]) * L2E;
        }
    }
    // rel_h (pre-scaled by log2e in relk): lane holds pair ki = sp*32 + r*2+{0,1}
    // for each of its 8 query rows (2 g x 4 reg)
    unsigned int rhv[2][4];
#pragma unroll
    for (int g = 0; g < 2; ++g)
#pragma unroll
        for (int reg = 0; reg < 4; ++reg)
            rhv[g][reg] = *(const unsigned int*)&rhb[
                (h * 4096 + qt * 128 + g * 64 + w * 16 + quad * 4 + reg) * 64
                + sp * 32 + r * 2];

    bf16x8 onesf;
#pragma unroll
    for (int i = 0; i < 8; ++i) onesf[i] = (short)0x3F80;  // bf16 1.0

    // stage tile 0 into buffer 0
#pragma unroll
    for (int gg = 0; gg < 2; ++gg) {
        const int g = w * 2 + gg;
        const int t0 = sp * 32;
        gl_lds16(kbuf + (h * 4096 + t0 * 64 + lane) * 64 + g * 8, &skb[0][g * 512]);
        gl_lds16(vtbuf + (h * 64 + lane) * 4096 + t0 * 64 + g * 8, &svb[0][g * 512]);
    }

    f32x4 lacc[2] = {};
    f32x4 oacc[2][4] = {};

#pragma unroll 1
    for (int tb = 0; tb < 16; ++tb) {
        // broadcast rel_h pair for tiles tb*2 and tb*2+1 (1 shfl per (g,reg))
        float rh2[2][2][4];  // [ti][g][reg]
#pragma unroll
        for (int g = 0; g < 2; ++g)
#pragma unroll
            for (int reg = 0; reg < 4; ++reg) {
                const unsigned int v =
                    (unsigned int)__shfl((int)rhv[g][reg], quad * 16 + tb, 64);
                rh2[0][g][reg] = lo16f(v);
                rh2[1][g][reg] = hi16f(v);
            }
#pragma unroll
        for (int ti = 0; ti < 2; ++ti) {
            const int tl = tb * 2 + ti;
            const int tn = (tl + 1) & 31;     // next tile (wraps: last restages 0)
            const int t  = sp * 32 + tl;
            const int tp = sp * 32 + tn;
            const int bc = ti, bn = ti ^ 1;
            // prefetch next tile into the other buffer (4 loads/wave in flight)
#pragma unroll
            for (int gg = 0; gg < 2; ++gg) {
                const int g = w * 2 + gg;
                gl_lds16(kbuf + (h * 4096 + tp * 64 + lane) * 64 + g * 8,
                         &skb[bn][g * 512]);
                gl_lds16(vtbuf + (h * 64 + lane) * 4096 + tp * 64 + g * 8,
                         &svb[bn][g * 512]);
            }
            // wait only for tile t's 4 loads; prefetch stays in flight
            asm volatile("s_waitcnt vmcnt(4)\n\ts_barrier" ::: "memory");

            // S for both qgroups; kf read once, used twice
            f32x4 s0[4] = {}, s1[4] = {};
#pragma unroll
            for (int s2 = 0; s2 < 2; ++s2) {
#pragma unroll
                for (int j = 0; j < 4; ++j) {
                    bf16x8 kf = *(const bf16x8*)&skb[bc][((s2 * 4 + quad) * 64 + j * 16 + r) * 8];
                    s0[j] = __builtin_amdgcn_mfma_f32_16x16x32_bf16(qf[0][s2], kf, s0[j], 0, 0, 0);
                    s1[j] = __builtin_amdgcn_mfma_f32_16x16x32_bf16(qf[1][s2], kf, s1[j], 0, 0, 0);
                }
            }
            // softmax + pack per qgroup (raw v_exp_f32; args bounded)
#pragma unroll
            for (int g = 0; g < 2; ++g) {
#pragma unroll
                for (int reg = 0; reg < 4; ++reg) {
                    unsigned int u[4];
#pragma unroll
                    for (int j = 0; j < 4; ++j) {
                        const float sv = g ? s1[j][reg] : s0[j][reg];
                        const float p = __builtin_amdgcn_exp2f(
                            fmaf(sv, SC, rh2[ti][g][reg] + rwL[g][j][reg]));
                        union { float f; unsigned int q; } cv; cv.f = p;
                        u[j] = cv.q;
                    }
                    u32x2 d;
                    d.x = __builtin_amdgcn_perm(u[1], u[0], 0x07060302);
                    d.y = __builtin_amdgcn_perm(u[3], u[2], 0x07060302);
                    *(u32x2*)&spb[g * 4608 + w * 1152 + (quad * 4 + reg) * 72 + r * 4] = d;
                }
            }
            // PV: vf read once, used twice; l row-sum via ones-MFMA
#pragma unroll
            for (int s = 0; s < 2; ++s) {
                bf16x8 pf0 = *(const bf16x8*)&spb[w * 1152 + r * 72 + s * 32 + quad * 8];
                bf16x8 pf1 = *(const bf16x8*)&spb[4608 + w * 1152 + r * 72 + s * 32 + quad * 8];
                lacc[0] = __builtin_amdgcn_mfma_f32_16x16x32_bf16(pf0, onesf, lacc[0], 0, 0, 0);
                lacc[1] = __builtin_amdgcn_mfma_f32_16x16x32_bf16(pf1, onesf, lacc[1], 0, 0, 0);
#pragma unroll
                for (int j = 0; j < 4; ++j) {
                    bf16x8 vf = *(const bf16x8*)&svb[bc][((s * 4 + quad) * 64 + j * 16 + r) * 8];
                    oacc[0][j] = __builtin_amdgcn_mfma_f32_16x16x32_bf16(pf0, vf, oacc[0][j], 0, 0, 0);
                    oacc[1][j] = __builtin_amdgcn_mfma_f32_16x16x32_bf16(pf1, vf, oacc[1][j], 0, 0, 0);
                }
            }
            // all waves done reading buffer bc before next iter overwrites it
            asm volatile("s_barrier" ::: "memory");
        }
    }
    // epilogue: store partials (lacc already holds full per-query row sums)
    const size_t pbase = ((size_t)(sp * 12 + h) * 4096 + qt * 128);
#pragma unroll
    for (int g = 0; g < 2; ++g) {
        const int qrow = g * 64 + w * 16 + quad * 4;
#pragma unroll
        for (int reg = 0; reg < 4; ++reg) {
#pragma unroll
            for (int j = 0; j < 4; ++j)
                po[(pbase + qrow + reg) * 64 + j * 16 + r] = oacc[g][j][reg];
            if (r == 0) lp[pbase + qrow + reg] = lacc[g][reg];
        }
    }
}

// ---------------------------------------------------------------------------
// Combine split-K partials: ab[t][h*64+d] = (po0+po1)/(l0+l1) as bf16.
// ---------------------------------------------------------------------------
__global__ __launch_bounds__(256) void combine(const float* __restrict__ po,
                                               const float* __restrict__ lp,
                                               unsigned short* __restrict__ ab) {
    const unsigned int idx = blockIdx.x * 256 + threadIdx.x;  // 0..393215
    const unsigned int tok = idx / 96u;
    const unsigned int part = idx - tok * 96u;
    const int c = part * 8, h = c >> 6, d = c & 63;
    const float* p0 = po + ((size_t)h * 4096 + tok) * 64 + d;
    const float* p1 = po + ((size_t)(12 + h) * 4096 + tok) * 64 + d;
    const float inv = 1.f / (lp[h * 4096 + tok] + lp[(12 + h) * 4096 + tok]);
    const float4 a0 = *(const float4*)p0, b0 = *(const float4*)(p0 + 4);
    const float4 a1 = *(const float4*)p1, b1 = *(const float4*)(p1 + 4);
    s16x4 o0, o1;
    o0[0] = (short)f2b((a0.x + a1.x) * inv); o0[1] = (short)f2b((a0.y + a1.y) * inv);
    o0[2] = (short)f2b((a0.z + a1.z) * inv); o0[3] = (short)f2b((a0.w + a1.w) * inv);
    o1[0] = (short)f2b((b0.x + b1.x) * inv); o1[1] = (short)f2b((b0.y + b1.y) * inv);
    o1[2] = (short)f2b((b0.z + b1.z) * inv); o1[3] = (short)f2b((b0.w + b1.w) * inv);
    unsigned short* dst = ab + (size_t)tok * 768 + c;
    *(s16x4*)dst = o0;
    *(s16x4*)(dst + 4) = o1;
}

// ---------------------------------------------------------------------------
extern "C" void kernel_launch(void* const* d_in, const int* in_sizes, int n_in,
                              void* d_out, int out_size, void* d_ws, size_t ws_size,
                              hipStream_t stream) {
    const float* hs  = (const float*)d_in[0];
    const float* wq  = (const float*)d_in[1];
    const float* bq  = (const float*)d_in[2];
    const float* wk  = (const float*)d_in[3];
    const float* bk  = (const float*)d_in[4];
    const float* wv  = (const float*)d_in[5];
    const float* bv  = (const float*)d_in[6];
    const float* wo  = (const float*)d_in[7];
    const float* bo  = (const float*)d_in[8];
    const float* rph = (const float*)d_in[9];
    const float* rpw = (const float*)d_in[10];

    unsigned short* ws = (unsigned short*)d_ws;
    const int HS = 3145728, WN = 589824, RP = 8128;
    const int HB = 12 * 4096 * 64;
    unsigned short* hsb  = ws;
    unsigned short* wqb  = hsb  + HS;
    unsigned short* wkb  = wqb  + WN;
    unsigned short* wvb  = wkb  + WN;
    unsigned short* wob  = wvb  + WN;
    unsigned short* rphb = wob  + WN;
    unsigned short* rpwb = rphb + RP;
    unsigned short* qb   = rpwb + RP;          // q   [h][t][d]
    unsigned short* kb   = qb   + HB;          // k   [h][t][d]
    unsigned short* vtb  = kb   + HB;          // v^T [h][d][t], token-permuted
    unsigned short* rhb  = vtb  + HB;          // rel_h*log2e [h][t][ki]
    unsigned short* rwb  = rhb  + HB;          // rel_w [h][t][kj]
    unsigned short* ab   = rwb  + HB;          // attn out [t][768]
    float* po = (float*)(ab + HB);             // O_num partials [2][12][4096][64]
    float* lp = po + 2 * 12 * 4096 * 64;       // l partials [2][12][4096]

    cvt_bf16<<<dim3((1380320 + 255) / 256), 256, 0, stream>>>(
        hs, wq, wk, wv, wo, rph, rpw, hsb);
    qkv128<<<dim3(6, 32, 3), 256, 0, stream>>>(
        hsb, wqb, wkb, wvb, bq, bk, bv, qb, kb, vtb);
    relk<<<dim3(64, 12, 2), 256, 0, stream>>>(qb, rphb, rpwb, rhb, rwb);
    attn2<<<dim3(32, 12, 2), 256, 0, stream>>>(qb, kb, vtb, rhb, rwb, po, lp);
    combine<<<dim3(1536), 256, 0, stream>>>(po, lp, ab);
    out128<<<dim3(6, 32), 256, 0, stream>>>(ab, wob, bo, (float*)d_out);
}